// Round 1
// baseline (511.350 us; speedup 1.0000x reference)
//
#include <hip/hip_runtime.h>

typedef __attribute__((ext_vector_type(8))) short short8;
typedef __attribute__((ext_vector_type(4))) float f32x4;

#define E2f   7.38905609893065f     // exp(2)
#define OSCALE 1.69864357f          // sqrt(2*log2(e)) ; dot of scaled rows = 2*log2(e)*dot

__device__ inline unsigned short f2bf(float f){
    union { float f; unsigned int u; } x; x.f = f;
    unsigned int u = x.u;
    return (unsigned short)((u + 0x7fffu + ((u >> 16) & 1u)) >> 16);
}

__device__ inline short8 pack8(float4 a, float4 b){
    short8 t;
    t[0]=(short)f2bf(a.x); t[1]=(short)f2bf(a.y); t[2]=(short)f2bf(a.z); t[3]=(short)f2bf(a.w);
    t[4]=(short)f2bf(b.x); t[5]=(short)f2bf(b.y); t[6]=(short)f2bf(b.z); t[7]=(short)f2bf(b.w);
    return t;
}

// ---- K0: cast+transpose W1 (512x128 -> 128x512 bf16) and W2 (128x128 -> 128x128 bf16)
__global__ __launch_bounds__(256) void k_prep(const float* __restrict__ W1, const float* __restrict__ W2,
                                              short* __restrict__ W1T, short* __restrict__ W2T){
    int idx = blockIdx.x*256 + threadIdx.x;
    if(idx < 512*128){
        int n = idx >> 9, k = idx & 511;
        W1T[idx] = (short)f2bf(W1[k*128 + n]);
    } else {
        int i2 = idx - 512*128;   // < 128*128
        int n = i2 >> 7, k = i2 & 127;
        W2T[i2] = (short)f2bf(W2[k*128 + n]);
    }
}

// ---- K1: h = doc @ W1 + b1 (bf16 MFMA), plus per-block BN partial sums
__global__ __launch_bounds__(256) void k_gemm1(const float* __restrict__ doc, const float* __restrict__ b1,
                                               const short* __restrict__ W1T, float* __restrict__ h,
                                               float* __restrict__ bsum, float* __restrict__ bsq){
    int bid = blockIdx.x;                   // 256 blocks, 64 rows each
    int tid = threadIdx.x;
    int w = tid >> 6, l = tid & 63, lr = l & 15, lk = l >> 4;
    int rowA = bid*64 + w*16 + lr;

    // hoist A fragments: 16 k-chunks of 32
    short8 a[16];
    const float* dp = doc + rowA*512 + lk*8;
    #pragma unroll
    for(int c=0;c<16;c++){
        float4 f0 = *(const float4*)(dp + c*32);
        float4 f1 = *(const float4*)(dp + c*32 + 4);
        a[c] = pack8(f0, f1);
    }

    f32x4 acc[8];
    #pragma unroll
    for(int ct=0; ct<8; ct++) acc[ct] = (f32x4){0.f,0.f,0.f,0.f};

    const short* wb = W1T + lr*512 + lk*8;
    #pragma unroll
    for(int c=0;c<16;c++){
        #pragma unroll
        for(int ct=0; ct<8; ct++){
            short8 b = *(const short8*)(wb + ct*16*512 + c*32);
            acc[ct] = __builtin_amdgcn_mfma_f32_16x16x32_bf16(a[c], b, acc[ct], 0,0,0);
        }
    }

    // epilogue: +b1, store h, BN partials
    __shared__ float lds_s[4][128];
    __shared__ float lds_q[4][128];
    int rowD = bid*64 + w*16 + lk*4;
    #pragma unroll
    for(int ct=0; ct<8; ct++){
        float bb = b1[ct*16 + lr];
        float s = 0.f, q = 0.f;
        #pragma unroll
        for(int r=0;r<4;r++){
            float v = acc[ct][r] + bb;
            h[(rowD + r)*128 + ct*16 + lr] = v;
            s += v; q += v*v;
        }
        // reduce over the 4 lane-groups (rows) for this column
        s += __shfl_xor(s,16); s += __shfl_xor(s,32);
        q += __shfl_xor(q,16); q += __shfl_xor(q,32);
        if(lk==0){ lds_s[w][ct*16+lr] = s; lds_q[w][ct*16+lr] = q; }
    }
    __syncthreads();
    if(tid < 128){
        float S = lds_s[0][tid]+lds_s[1][tid]+lds_s[2][tid]+lds_s[3][tid];
        float Q = lds_q[0][tid]+lds_q[1][tid]+lds_q[2][tid]+lds_q[3][tid];
        bsum[bid*128 + tid] = S;
        bsq [bid*128 + tid] = Q;
    }
}

// ---- K2: finalize BN params
__global__ __launch_bounds__(128) void k_bnfin(const float* __restrict__ bsum, const float* __restrict__ bsq,
                                               const float* __restrict__ gamma, const float* __restrict__ beta,
                                               float* __restrict__ bnA, float* __restrict__ bnB){
    int c = threadIdx.x;
    float S=0.f, Q=0.f;
    for(int b=0;b<256;b++){ S += bsum[b*128+c]; Q += bsq[b*128+c]; }
    float mu = S * (1.0f/16384.0f);
    float var = Q * (1.0f/16384.0f) - mu*mu;
    float A = gamma[c] * rsqrtf(var + 1e-5f);
    bnA[c] = A;
    bnB[c] = beta[c] - mu*A;
}

// ---- K3: BN+ReLU -> GEMM2 -> +b2 -> L2 normalize -> pair dots d[i] -> scaled bf16 o1s/o2s
__global__ __launch_bounds__(256) void k_gemm2(const float* __restrict__ h, const short* __restrict__ W2T,
                                               const float* __restrict__ bnA, const float* __restrict__ bnB,
                                               const float* __restrict__ b2,
                                               short* __restrict__ o1s, short* __restrict__ o2s,
                                               float* __restrict__ dvec){
    int bid = blockIdx.x;
    int tid = threadIdx.x;
    int w = tid >> 6, l = tid & 63, lr = l & 15, lk = l >> 4;
    int rowA = bid*64 + w*16 + lr;

    short8 a[4];
    const float* hp = h + rowA*128 + lk*8;
    #pragma unroll
    for(int c=0;c<4;c++){
        float4 h0 = *(const float4*)(hp + c*32);
        float4 h1 = *(const float4*)(hp + c*32 + 4);
        float4 A0 = *(const float4*)(bnA + c*32 + lk*8);
        float4 A1 = *(const float4*)(bnA + c*32 + lk*8 + 4);
        float4 B0 = *(const float4*)(bnB + c*32 + lk*8);
        float4 B1 = *(const float4*)(bnB + c*32 + lk*8 + 4);
        float4 v0, v1;
        v0.x = fmaxf(h0.x*A0.x + B0.x, 0.f); v0.y = fmaxf(h0.y*A0.y + B0.y, 0.f);
        v0.z = fmaxf(h0.z*A0.z + B0.z, 0.f); v0.w = fmaxf(h0.w*A0.w + B0.w, 0.f);
        v1.x = fmaxf(h1.x*A1.x + B1.x, 0.f); v1.y = fmaxf(h1.y*A1.y + B1.y, 0.f);
        v1.z = fmaxf(h1.z*A1.z + B1.z, 0.f); v1.w = fmaxf(h1.w*A1.w + B1.w, 0.f);
        a[c] = pack8(v0, v1);
    }

    f32x4 acc[8];
    #pragma unroll
    for(int ct=0; ct<8; ct++) acc[ct] = (f32x4){0.f,0.f,0.f,0.f};
    const short* wb = W2T + lr*128 + lk*8;
    #pragma unroll
    for(int c=0;c<4;c++){
        #pragma unroll
        for(int ct=0; ct<8; ct++){
            short8 b = *(const short8*)(wb + ct*16*128 + c*32);
            acc[ct] = __builtin_amdgcn_mfma_f32_16x16x32_bf16(a[c], b, acc[ct], 0,0,0);
        }
    }

    // + b2
    #pragma unroll
    for(int ct=0; ct<8; ct++){
        float bb = b2[ct*16 + lr];
        #pragma unroll
        for(int r=0;r<4;r++) acc[ct][r] += bb;
    }
    // row sums of squares (reduce over 16 lanes = 128 cols)
    float n2[4] = {0.f,0.f,0.f,0.f};
    #pragma unroll
    for(int ct=0; ct<8; ct++){
        #pragma unroll
        for(int r=0;r<4;r++) n2[r] += acc[ct][r]*acc[ct][r];
    }
    #pragma unroll
    for(int r=0;r<4;r++){
        n2[r] += __shfl_xor(n2[r],1); n2[r] += __shfl_xor(n2[r],2);
        n2[r] += __shfl_xor(n2[r],4); n2[r] += __shfl_xor(n2[r],8);
    }
    float sc[4];
    #pragma unroll
    for(int r=0;r<4;r++) sc[r] = 1.0f / fmaxf(sqrtf(n2[r]), 1e-12f);
    #pragma unroll
    for(int ct=0; ct<8; ct++){
        #pragma unroll
        for(int r=0;r<4;r++) acc[ct][r] *= sc[r];
    }
    // pair dots: rows (2p even, 2p+1 odd) are adjacent regs
    float dp0 = 0.f, dp1 = 0.f;
    #pragma unroll
    for(int ct=0; ct<8; ct++){
        dp0 += acc[ct][0]*acc[ct][1];
        dp1 += acc[ct][2]*acc[ct][3];
    }
    dp0 += __shfl_xor(dp0,1); dp0 += __shfl_xor(dp0,2); dp0 += __shfl_xor(dp0,4); dp0 += __shfl_xor(dp0,8);
    dp1 += __shfl_xor(dp1,1); dp1 += __shfl_xor(dp1,2); dp1 += __shfl_xor(dp1,4); dp1 += __shfl_xor(dp1,8);
    int r0 = bid*64 + w*16 + lk*4;
    if(lr==0){
        dvec[(r0>>1)    ] = dp0;
        dvec[(r0>>1) + 1] = dp1;
    }
    // store scaled bf16, deinterleaved (odd rows -> o1s, even -> o2s)
    #pragma unroll
    for(int ct=0; ct<8; ct++){
        #pragma unroll
        for(int r=0;r<4;r++){
            int grow = r0 + r;
            int col  = ct*16 + lr;
            short bits = (short)f2bf(acc[ct][r] * OSCALE);
            if(grow & 1) o1s[(grow>>1)*128 + col] = bits;
            else         o2s[(grow>>1)*128 + col] = bits;
        }
    }
}

// ---- K4: rowsum of exp(2*dot) = exp2(dot_scaled) over j; partials per j-split (deterministic)
__global__ __launch_bounds__(256) void k_expsum(const short* __restrict__ A, const short* __restrict__ B,
                                                float* __restrict__ rpart){
    int bx = blockIdx.x, by = blockIdx.y;   // bx: 128 row-blocks, by: 8 j-splits
    int tid = threadIdx.x;
    int w = tid >> 6, l = tid & 63, lr = l & 15, lk = l >> 4;
    int rowA = bx*64 + w*16 + lr;

    short8 a0 = *(const short8*)(A + rowA*128 +  0 + lk*8);
    short8 a1 = *(const short8*)(A + rowA*128 + 32 + lk*8);
    short8 a2 = *(const short8*)(A + rowA*128 + 64 + lk*8);
    short8 a3 = *(const short8*)(A + rowA*128 + 96 + lk*8);

    float rs0=0.f, rs1=0.f, rs2=0.f, rs3=0.f;
    const short* Bbase = B + (by*1024 + lr)*128 + lk*8;

    for(int jt=0; jt<64; jt+=2){
        const short* bp0 = Bbase + jt*2048;      // 16 rows * 128
        const short* bp1 = bp0 + 2048;
        f32x4 c0 = (f32x4){0.f,0.f,0.f,0.f};
        f32x4 c1 = (f32x4){0.f,0.f,0.f,0.f};
        c0 = __builtin_amdgcn_mfma_f32_16x16x32_bf16(a0, *(const short8*)(bp0     ), c0,0,0,0);
        c1 = __builtin_amdgcn_mfma_f32_16x16x32_bf16(a0, *(const short8*)(bp1     ), c1,0,0,0);
        c0 = __builtin_amdgcn_mfma_f32_16x16x32_bf16(a1, *(const short8*)(bp0 + 32), c0,0,0,0);
        c1 = __builtin_amdgcn_mfma_f32_16x16x32_bf16(a1, *(const short8*)(bp1 + 32), c1,0,0,0);
        c0 = __builtin_amdgcn_mfma_f32_16x16x32_bf16(a2, *(const short8*)(bp0 + 64), c0,0,0,0);
        c1 = __builtin_amdgcn_mfma_f32_16x16x32_bf16(a2, *(const short8*)(bp1 + 64), c1,0,0,0);
        c0 = __builtin_amdgcn_mfma_f32_16x16x32_bf16(a3, *(const short8*)(bp0 + 96), c0,0,0,0);
        c1 = __builtin_amdgcn_mfma_f32_16x16x32_bf16(a3, *(const short8*)(bp1 + 96), c1,0,0,0);
        rs0 += exp2f(c0[0]) + exp2f(c1[0]);
        rs1 += exp2f(c0[1]) + exp2f(c1[1]);
        rs2 += exp2f(c0[2]) + exp2f(c1[2]);
        rs3 += exp2f(c0[3]) + exp2f(c1[3]);
    }
    rs0 += __shfl_xor(rs0,1); rs0 += __shfl_xor(rs0,2); rs0 += __shfl_xor(rs0,4); rs0 += __shfl_xor(rs0,8);
    rs1 += __shfl_xor(rs1,1); rs1 += __shfl_xor(rs1,2); rs1 += __shfl_xor(rs1,4); rs1 += __shfl_xor(rs1,8);
    rs2 += __shfl_xor(rs2,1); rs2 += __shfl_xor(rs2,2); rs2 += __shfl_xor(rs2,4); rs2 += __shfl_xor(rs2,8);
    rs3 += __shfl_xor(rs3,1); rs3 += __shfl_xor(rs3,2); rs3 += __shfl_xor(rs3,4); rs3 += __shfl_xor(rs3,8);
    if(lr==0){
        float4 v; v.x=rs0; v.y=rs1; v.z=rs2; v.w=rs3;
        *(float4*)(rpart + by*8192 + bx*64 + w*16 + lk*4) = v;
    }
}

// ---- K5: per-pair loss + block partial sums
__global__ __launch_bounds__(256) void k_loss1(const float* __restrict__ r11, const float* __restrict__ r12,
                                               const float* __restrict__ r21, const float* __restrict__ r22,
                                               const float* __restrict__ dvec, float* __restrict__ lpart){
    int i = blockIdx.x*256 + threadIdx.x;
    float s11=0.f, s12=0.f, s21=0.f, s22=0.f;
    #pragma unroll
    for(int s=0;s<8;s++){
        s11 += r11[s*8192+i]; s12 += r12[s*8192+i];
        s21 += r21[s*8192+i]; s22 += r22[s*8192+i];
    }
    float d1 = s11 - E2f + s12;
    float d2 = s22 - E2f + s21;
    float loss = 0.5f*(logf(d1)+logf(d2)) - 2.0f*dvec[i];
    loss += __shfl_xor(loss,1);  loss += __shfl_xor(loss,2);  loss += __shfl_xor(loss,4);
    loss += __shfl_xor(loss,8);  loss += __shfl_xor(loss,16); loss += __shfl_xor(loss,32);
    __shared__ float lds[4];
    if((threadIdx.x & 63) == 0) lds[threadIdx.x >> 6] = loss;
    __syncthreads();
    if(threadIdx.x == 0) lpart[blockIdx.x] = lds[0]+lds[1]+lds[2]+lds[3];
}

__global__ __launch_bounds__(64) void k_loss2(const float* __restrict__ lpart, float* __restrict__ out){
    if(threadIdx.x == 0){
        float s = 0.f;
        for(int i=0;i<32;i++) s += lpart[i];
        out[0] = s * (1.0f/8192.0f);
    }
}

extern "C" void kernel_launch(void* const* d_in, const int* in_sizes, int n_in,
                              void* d_out, int out_size, void* d_ws, size_t ws_size,
                              hipStream_t stream){
    (void)in_sizes; (void)n_in; (void)out_size; (void)ws_size;
    const float* doc   = (const float*)d_in[0];
    const float* W1    = (const float*)d_in[1];
    const float* b1    = (const float*)d_in[2];
    const float* gamma = (const float*)d_in[3];
    const float* beta  = (const float*)d_in[4];
    const float* W2    = (const float*)d_in[5];
    const float* b2    = (const float*)d_in[6];
    float* out = (float*)d_out;

    char* ws = (char*)d_ws;
    float* h     = (float*)(ws + 0);            // 16384*128*4 = 8388608
    short* W1T   = (short*)(ws + 8388608);      // 128*512*2  = 131072
    short* W2T   = (short*)(ws + 8519680);      // 128*128*2  = 32768
    short* o1s   = (short*)(ws + 8552448);      // 8192*128*2 = 2097152
    short* o2s   = (short*)(ws + 10649600);     // 2097152
    float* dvec  = (float*)(ws + 12746752);     // 8192*4 = 32768
    float* bnA   = (float*)(ws + 12779520);     // 512
    float* bnB   = (float*)(ws + 12780032);     // 512
    float* bsum  = (float*)(ws + 12780544);     // 256*128*4 = 131072
    float* bsq   = (float*)(ws + 12911616);     // 131072
    float* r11p  = (float*)(ws + 13042688);     // 8*8192*4 = 262144
    float* r12p  = (float*)(ws + 13304832);
    float* r21p  = (float*)(ws + 13566976);
    float* r22p  = (float*)(ws + 13829120);
    float* lpart = (float*)(ws + 14091264);     // 128

    k_prep <<<320, 256, 0, stream>>>(W1, W2, W1T, W2T);
    k_gemm1<<<256, 256, 0, stream>>>(doc, b1, W1T, h, bsum, bsq);
    k_bnfin<<<1, 128, 0, stream>>>(bsum, bsq, gamma, beta, bnA, bnB);
    k_gemm2<<<256, 256, 0, stream>>>(h, W2T, bnA, bnB, b2, o1s, o2s, dvec);
    dim3 eg(128, 8);
    k_expsum<<<eg, 256, 0, stream>>>(o1s, o1s, r11p);
    k_expsum<<<eg, 256, 0, stream>>>(o1s, o2s, r12p);
    k_expsum<<<eg, 256, 0, stream>>>(o2s, o1s, r21p);
    k_expsum<<<eg, 256, 0, stream>>>(o2s, o2s, r22p);
    k_loss1<<<32, 256, 0, stream>>>(r11p, r12p, r21p, r22p, dvec, lpart);
    k_loss2<<<1, 64, 0, stream>>>(lpart, out);
}

// Round 2
// 129.119 us; speedup vs baseline: 3.9603x; 3.9603x over previous
//
#include <hip/hip_runtime.h>

typedef __attribute__((ext_vector_type(8))) short short8;
typedef __attribute__((ext_vector_type(4))) float f32x4;

typedef const __attribute__((address_space(1))) unsigned int as1_u32;
typedef __attribute__((address_space(3))) unsigned int as3_u32;

#define E2f   7.38905609893065f     // exp(2)
#define OSCALE 1.69864357f          // sqrt(2*log2(e)) ; dot of scaled rows = 2*log2(e)*dot

#if __has_builtin(__builtin_amdgcn_exp2f)
#define EXP2(x) __builtin_amdgcn_exp2f(x)
#else
#define EXP2(x) exp2f(x)
#endif

__device__ inline unsigned short f2bf(float f){
    union { float f; unsigned int u; } x; x.f = f;
    unsigned int u = x.u;
    return (unsigned short)((u + 0x7fffu + ((u >> 16) & 1u)) >> 16);
}

__device__ inline short8 pack8(float4 a, float4 b){
    short8 t;
    t[0]=(short)f2bf(a.x); t[1]=(short)f2bf(a.y); t[2]=(short)f2bf(a.z); t[3]=(short)f2bf(a.w);
    t[4]=(short)f2bf(b.x); t[5]=(short)f2bf(b.y); t[6]=(short)f2bf(b.z); t[7]=(short)f2bf(b.w);
    return t;
}

// ---- K0: cast+transpose W1 (512x128 -> 128x512 bf16) and W2 (128x128 -> 128x128 bf16)
__global__ __launch_bounds__(256) void k_prep(const float* __restrict__ W1, const float* __restrict__ W2,
                                              short* __restrict__ W1T, short* __restrict__ W2T){
    int idx = blockIdx.x*256 + threadIdx.x;
    if(idx < 512*128){
        int n = idx >> 9, k = idx & 511;
        W1T[idx] = (short)f2bf(W1[k*128 + n]);
    } else {
        int i2 = idx - 512*128;   // < 128*128
        int n = i2 >> 7, k = i2 & 127;
        W2T[i2] = (short)f2bf(W2[k*128 + n]);
    }
}

// ---- K1: h = doc @ W1 + b1 (bf16 MFMA), plus per-block BN partial sums
__global__ __launch_bounds__(256) void k_gemm1(const float* __restrict__ doc, const float* __restrict__ b1,
                                               const short* __restrict__ W1T, float* __restrict__ h,
                                               float* __restrict__ bsum, float* __restrict__ bsq){
    int bid = blockIdx.x;                   // 256 blocks, 64 rows each
    int tid = threadIdx.x;
    int w = tid >> 6, l = tid & 63, lr = l & 15, lk = l >> 4;
    int rowA = bid*64 + w*16 + lr;

    short8 a[16];
    const float* dp = doc + rowA*512 + lk*8;
    #pragma unroll
    for(int c=0;c<16;c++){
        float4 f0 = *(const float4*)(dp + c*32);
        float4 f1 = *(const float4*)(dp + c*32 + 4);
        a[c] = pack8(f0, f1);
    }

    f32x4 acc[8];
    #pragma unroll
    for(int ct=0; ct<8; ct++) acc[ct] = (f32x4){0.f,0.f,0.f,0.f};

    const short* wb = W1T + lr*512 + lk*8;
    #pragma unroll
    for(int c=0;c<16;c++){
        #pragma unroll
        for(int ct=0; ct<8; ct++){
            short8 b = *(const short8*)(wb + ct*16*512 + c*32);
            acc[ct] = __builtin_amdgcn_mfma_f32_16x16x32_bf16(a[c], b, acc[ct], 0,0,0);
        }
    }

    __shared__ float lds_s[4][128];
    __shared__ float lds_q[4][128];
    int rowD = bid*64 + w*16 + lk*4;
    #pragma unroll
    for(int ct=0; ct<8; ct++){
        float bb = b1[ct*16 + lr];
        float s = 0.f, q = 0.f;
        #pragma unroll
        for(int r=0;r<4;r++){
            float v = acc[ct][r] + bb;
            h[(rowD + r)*128 + ct*16 + lr] = v;
            s += v; q += v*v;
        }
        s += __shfl_xor(s,16); s += __shfl_xor(s,32);
        q += __shfl_xor(q,16); q += __shfl_xor(q,32);
        if(lk==0){ lds_s[w][ct*16+lr] = s; lds_q[w][ct*16+lr] = q; }
    }
    __syncthreads();
    if(tid < 128){
        float S = lds_s[0][tid]+lds_s[1][tid]+lds_s[2][tid]+lds_s[3][tid];
        float Q = lds_q[0][tid]+lds_q[1][tid]+lds_q[2][tid]+lds_q[3][tid];
        bsum[bid*128 + tid] = S;
        bsq [bid*128 + tid] = Q;
    }
}

// ---- K2: finalize BN params
__global__ __launch_bounds__(128) void k_bnfin(const float* __restrict__ bsum, const float* __restrict__ bsq,
                                               const float* __restrict__ gamma, const float* __restrict__ beta,
                                               float* __restrict__ bnA, float* __restrict__ bnB){
    int c = threadIdx.x;
    float S=0.f, Q=0.f;
    for(int b=0;b<256;b++){ S += bsum[b*128+c]; Q += bsq[b*128+c]; }
    float mu = S * (1.0f/16384.0f);
    float var = Q * (1.0f/16384.0f) - mu*mu;
    float A = gamma[c] * rsqrtf(var + 1e-5f);
    bnA[c] = A;
    bnB[c] = beta[c] - mu*A;
}

// ---- K3: BN+ReLU -> GEMM2 -> +b2 -> L2 normalize -> pair dots -> scaled bf16 o1s/o2s
__global__ __launch_bounds__(256) void k_gemm2(const float* __restrict__ h, const short* __restrict__ W2T,
                                               const float* __restrict__ bnA, const float* __restrict__ bnB,
                                               const float* __restrict__ b2,
                                               short* __restrict__ o1s, short* __restrict__ o2s,
                                               float* __restrict__ dvec){
    int bid = blockIdx.x;
    int tid = threadIdx.x;
    int w = tid >> 6, l = tid & 63, lr = l & 15, lk = l >> 4;
    int rowA = bid*64 + w*16 + lr;

    short8 a[4];
    const float* hp = h + rowA*128 + lk*8;
    #pragma unroll
    for(int c=0;c<4;c++){
        float4 h0 = *(const float4*)(hp + c*32);
        float4 h1 = *(const float4*)(hp + c*32 + 4);
        float4 A0 = *(const float4*)(bnA + c*32 + lk*8);
        float4 A1 = *(const float4*)(bnA + c*32 + lk*8 + 4);
        float4 B0 = *(const float4*)(bnB + c*32 + lk*8);
        float4 B1 = *(const float4*)(bnB + c*32 + lk*8 + 4);
        float4 v0, v1;
        v0.x = fmaxf(h0.x*A0.x + B0.x, 0.f); v0.y = fmaxf(h0.y*A0.y + B0.y, 0.f);
        v0.z = fmaxf(h0.z*A0.z + B0.z, 0.f); v0.w = fmaxf(h0.w*A0.w + B0.w, 0.f);
        v1.x = fmaxf(h1.x*A1.x + B1.x, 0.f); v1.y = fmaxf(h1.y*A1.y + B1.y, 0.f);
        v1.z = fmaxf(h1.z*A1.z + B1.z, 0.f); v1.w = fmaxf(h1.w*A1.w + B1.w, 0.f);
        a[c] = pack8(v0, v1);
    }

    f32x4 acc[8];
    #pragma unroll
    for(int ct=0; ct<8; ct++) acc[ct] = (f32x4){0.f,0.f,0.f,0.f};
    const short* wb = W2T + lr*128 + lk*8;
    #pragma unroll
    for(int c=0;c<4;c++){
        #pragma unroll
        for(int ct=0; ct<8; ct++){
            short8 b = *(const short8*)(wb + ct*16*128 + c*32);
            acc[ct] = __builtin_amdgcn_mfma_f32_16x16x32_bf16(a[c], b, acc[ct], 0,0,0);
        }
    }

    #pragma unroll
    for(int ct=0; ct<8; ct++){
        float bb = b2[ct*16 + lr];
        #pragma unroll
        for(int r=0;r<4;r++) acc[ct][r] += bb;
    }
    float n2[4] = {0.f,0.f,0.f,0.f};
    #pragma unroll
    for(int ct=0; ct<8; ct++){
        #pragma unroll
        for(int r=0;r<4;r++) n2[r] += acc[ct][r]*acc[ct][r];
    }
    #pragma unroll
    for(int r=0;r<4;r++){
        n2[r] += __shfl_xor(n2[r],1); n2[r] += __shfl_xor(n2[r],2);
        n2[r] += __shfl_xor(n2[r],4); n2[r] += __shfl_xor(n2[r],8);
    }
    float sc[4];
    #pragma unroll
    for(int r=0;r<4;r++) sc[r] = 1.0f / fmaxf(sqrtf(n2[r]), 1e-12f);
    #pragma unroll
    for(int ct=0; ct<8; ct++){
        #pragma unroll
        for(int r=0;r<4;r++) acc[ct][r] *= sc[r];
    }
    float dp0 = 0.f, dp1 = 0.f;
    #pragma unroll
    for(int ct=0; ct<8; ct++){
        dp0 += acc[ct][0]*acc[ct][1];
        dp1 += acc[ct][2]*acc[ct][3];
    }
    dp0 += __shfl_xor(dp0,1); dp0 += __shfl_xor(dp0,2); dp0 += __shfl_xor(dp0,4); dp0 += __shfl_xor(dp0,8);
    dp1 += __shfl_xor(dp1,1); dp1 += __shfl_xor(dp1,2); dp1 += __shfl_xor(dp1,4); dp1 += __shfl_xor(dp1,8);
    int r0 = bid*64 + w*16 + lk*4;
    if(lr==0){
        dvec[(r0>>1)    ] = dp0;
        dvec[(r0>>1) + 1] = dp1;
    }
    #pragma unroll
    for(int ct=0; ct<8; ct++){
        #pragma unroll
        for(int r=0;r<4;r++){
            int grow = r0 + r;
            int col  = ct*16 + lr;
            short bits = (short)f2bf(acc[ct][r] * OSCALE);
            if(grow & 1) o1s[(grow>>1)*128 + col] = bits;
            else         o2s[(grow>>1)*128 + col] = bits;
        }
    }
}

// ---- K4: fused similarity pass. grid (64, 16, 3).
//  z=0: rowsum exp(o1 o1^T) -> r11p[by][row]
//  z=1: rowsum exp(o2 o2^T) -> r22p[by][row]
//  z=2: rowsum exp(o1 o2^T) -> r12p[by][row]  AND colsum -> c12p[bx][col]
// 128 A-rows/block in regs; B double-buffered in LDS via global_load_lds with
// pre-swizzled global source (rule 21) + XOR-swizzled ds_read (bank-even).
__global__ __launch_bounds__(256) void k_sim(const short* __restrict__ o1s, const short* __restrict__ o2s,
                                             float* __restrict__ r11p, float* __restrict__ r22p,
                                             float* __restrict__ r12p, float* __restrict__ c12p){
    int bx = blockIdx.x, by = blockIdx.y, pz = blockIdx.z;
    const short* A = (pz==1) ? o2s : o1s;
    const short* B = (pz==0) ? o1s : o2s;
    float* rowp = (pz==0) ? r11p : (pz==1 ? r22p : r12p);
    const bool colsum = (pz==2);

    int tid = threadIdx.x;
    int w = tid>>6, l = tid&63, lr = l&15, lk = l>>4;

    __shared__ __align__(16) short lds[2][8192];   // 2 x 64 rows x 128 bf16
    __shared__ float cs_lds[2][4][64];

    // A fragments: rows bx*128 + w*32 + rt*16 + lr
    short8 a[2][4];
    {
        const short* ap = A + (bx*128 + w*32 + lr)*128 + lk*8;
        #pragma unroll
        for(int rt=0;rt<2;rt++)
            #pragma unroll
            for(int c=0;c<4;c++)
                a[rt][c] = *(const short8*)(ap + rt*2048 + c*32);
    }

    // swizzled ds_read byte offsets per k-chunk c
    int sb[4];
    #pragma unroll
    for(int c=0;c<4;c++) sb[c] = lr*256 + ((((c*4+lk) ^ (lr&7)))<<4);

    // staging source pointers (4 issues/wave); source col16 pre-swizzled so
    // the linear global_load_lds dest yields LDS[row][s] = B[row][s ^ (row&7)]
    const short* gsrc[4];
    #pragma unroll
    for(int i=0;i<4;i++){
        int chunk = i*4 + w;              // 1KB chunk = 4 rows
        int row = chunk*4 + (l>>4);
        int col16 = (l&15) ^ (row&7);
        gsrc[i] = B + (by*512 + row)*128 + col16*8;
    }

    // stage tile 0
    #pragma unroll
    for(int i=0;i<4;i++){
        __builtin_amdgcn_global_load_lds((as1_u32*)gsrc[i],
            (as3_u32*)(&lds[0][(i*4+w)*512]), 16, 0, 0);
        gsrc[i] += 8192;   // next 64-row tile
    }
    asm volatile("s_waitcnt vmcnt(0)" ::: "memory");
    __syncthreads();

    float rs[2][4] = {{0.f,0.f,0.f,0.f},{0.f,0.f,0.f,0.f}};
    int buf = 0;
    const char* lbase = (const char*)&lds[0][0];

    for(int t=0;t<8;t++){
        if(t<7){
            #pragma unroll
            for(int i=0;i<4;i++){
                __builtin_amdgcn_global_load_lds((as1_u32*)gsrc[i],
                    (as3_u32*)(&lds[buf^1][(i*4+w)*512]), 16, 0, 0);
                gsrc[i] += 8192;
            }
        }
        const char* lb = lbase + buf*16384;
        #pragma unroll
        for(int jt=0;jt<4;jt++){
            short8 b0 = *(const short8*)(lb + jt*4096 + sb[0]);
            short8 b1 = *(const short8*)(lb + jt*4096 + sb[1]);
            short8 b2 = *(const short8*)(lb + jt*4096 + sb[2]);
            short8 b3 = *(const short8*)(lb + jt*4096 + sb[3]);
            f32x4 c0 = (f32x4){0.f,0.f,0.f,0.f};
            f32x4 c1 = (f32x4){0.f,0.f,0.f,0.f};
            c0 = __builtin_amdgcn_mfma_f32_16x16x32_bf16(a[0][0], b0, c0,0,0,0);
            c1 = __builtin_amdgcn_mfma_f32_16x16x32_bf16(a[1][0], b0, c1,0,0,0);
            c0 = __builtin_amdgcn_mfma_f32_16x16x32_bf16(a[0][1], b1, c0,0,0,0);
            c1 = __builtin_amdgcn_mfma_f32_16x16x32_bf16(a[1][1], b1, c1,0,0,0);
            c0 = __builtin_amdgcn_mfma_f32_16x16x32_bf16(a[0][2], b2, c0,0,0,0);
            c1 = __builtin_amdgcn_mfma_f32_16x16x32_bf16(a[1][2], b2, c1,0,0,0);
            c0 = __builtin_amdgcn_mfma_f32_16x16x32_bf16(a[0][3], b3, c0,0,0,0);
            c1 = __builtin_amdgcn_mfma_f32_16x16x32_bf16(a[1][3], b3, c1,0,0,0);
            float e00 = EXP2(c0[0]), e01 = EXP2(c0[1]), e02 = EXP2(c0[2]), e03 = EXP2(c0[3]);
            float e10 = EXP2(c1[0]), e11 = EXP2(c1[1]), e12 = EXP2(c1[2]), e13 = EXP2(c1[3]);
            rs[0][0]+=e00; rs[0][1]+=e01; rs[0][2]+=e02; rs[0][3]+=e03;
            rs[1][0]+=e10; rs[1][1]+=e11; rs[1][2]+=e12; rs[1][3]+=e13;
            if(colsum){
                float cv = ((e00+e01)+(e02+e03)) + ((e10+e11)+(e12+e13));
                cv += __shfl_xor(cv,16); cv += __shfl_xor(cv,32);
                if(lk==0) cs_lds[t&1][w][jt*16+lr] = cv;
            }
        }
        asm volatile("s_waitcnt vmcnt(0)" ::: "memory");
        __syncthreads();
        if(colsum && tid < 64){
            float v = cs_lds[t&1][0][tid]+cs_lds[t&1][1][tid]
                    + cs_lds[t&1][2][tid]+cs_lds[t&1][3][tid];
            c12p[bx*8192 + by*512 + t*64 + tid] = v;
        }
        buf ^= 1;
    }

    // rowsum: reduce over the 16 j-lanes, store per-split partial
    #pragma unroll
    for(int rt=0;rt<2;rt++){
        #pragma unroll
        for(int r=0;r<4;r++){
            rs[rt][r] += __shfl_xor(rs[rt][r],1);
            rs[rt][r] += __shfl_xor(rs[rt][r],2);
            rs[rt][r] += __shfl_xor(rs[rt][r],4);
            rs[rt][r] += __shfl_xor(rs[rt][r],8);
        }
        if(lr==0){
            float4 v; v.x=rs[rt][0]; v.y=rs[rt][1]; v.z=rs[rt][2]; v.w=rs[rt][3];
            *(float4*)(rowp + by*8192 + bx*128 + w*32 + rt*16 + lk*4) = v;
        }
    }
}

// ---- K5: per-pair loss + block partial sums
__global__ __launch_bounds__(256) void k_loss1(const float* __restrict__ r11, const float* __restrict__ r12,
                                               const float* __restrict__ r22, const float* __restrict__ c12,
                                               const float* __restrict__ dvec, float* __restrict__ lpart){
    int i = blockIdx.x*256 + threadIdx.x;
    float s11=0.f, s12=0.f, s22=0.f, s21=0.f;
    #pragma unroll
    for(int s=0;s<16;s++){
        s11 += r11[s*8192+i]; s12 += r12[s*8192+i]; s22 += r22[s*8192+i];
    }
    #pragma unroll
    for(int s=0;s<64;s++) s21 += c12[s*8192+i];
    float d1 = s11 - E2f + s12;
    float d2 = s22 - E2f + s21;
    float loss = 0.5f*(logf(d1)+logf(d2)) - 2.0f*dvec[i];
    loss += __shfl_xor(loss,1);  loss += __shfl_xor(loss,2);  loss += __shfl_xor(loss,4);
    loss += __shfl_xor(loss,8);  loss += __shfl_xor(loss,16); loss += __shfl_xor(loss,32);
    __shared__ float lds[4];
    if((threadIdx.x & 63) == 0) lds[threadIdx.x >> 6] = loss;
    __syncthreads();
    if(threadIdx.x == 0) lpart[blockIdx.x] = lds[0]+lds[1]+lds[2]+lds[3];
}

__global__ __launch_bounds__(64) void k_loss2(const float* __restrict__ lpart, float* __restrict__ out){
    if(threadIdx.x == 0){
        float s = 0.f;
        for(int i=0;i<32;i++) s += lpart[i];
        out[0] = s * (1.0f/8192.0f);
    }
}

extern "C" void kernel_launch(void* const* d_in, const int* in_sizes, int n_in,
                              void* d_out, int out_size, void* d_ws, size_t ws_size,
                              hipStream_t stream){
    (void)in_sizes; (void)n_in; (void)out_size; (void)ws_size;
    const float* doc   = (const float*)d_in[0];
    const float* W1    = (const float*)d_in[1];
    const float* b1    = (const float*)d_in[2];
    const float* gamma = (const float*)d_in[3];
    const float* beta  = (const float*)d_in[4];
    const float* W2    = (const float*)d_in[5];
    const float* b2    = (const float*)d_in[6];
    float* out = (float*)d_out;

    char* ws = (char*)d_ws;
    // region [0, 8388608): h (live k_gemm1..k_gemm2), then reused by k_sim partials
    float* h     = (float*)(ws + 0);            // 16384*128*4 = 8388608
    float* c12p  = (float*)(ws + 0);            // 64*8192*4 = 2097152   (after h dead)
    float* r11p  = (float*)(ws + 2097152);      // 16*8192*4 = 524288
    float* r22p  = (float*)(ws + 2621440);      // 524288
    float* r12p  = (float*)(ws + 3145728);      // 524288
    short* W1T   = (short*)(ws + 8388608);      // 128*512*2  = 131072
    short* W2T   = (short*)(ws + 8519680);      // 128*128*2  = 32768
    short* o1s   = (short*)(ws + 8552448);      // 8192*128*2 = 2097152
    short* o2s   = (short*)(ws + 10649600);     // 2097152
    float* dvec  = (float*)(ws + 12746752);     // 8192*4 = 32768
    float* bnA   = (float*)(ws + 12779520);     // 512
    float* bnB   = (float*)(ws + 12780032);     // 512
    float* bsum  = (float*)(ws + 12780544);     // 256*128*4 = 131072
    float* bsq   = (float*)(ws + 12911616);     // 131072
    float* lpart = (float*)(ws + 13042688);     // 128

    k_prep <<<320, 256, 0, stream>>>(W1, W2, W1T, W2T);
    k_gemm1<<<256, 256, 0, stream>>>(doc, b1, W1T, h, bsum, bsq);
    k_bnfin<<<1, 128, 0, stream>>>(bsum, bsq, gamma, beta, bnA, bnB);
    k_gemm2<<<256, 256, 0, stream>>>(h, W2T, bnA, bnB, b2, o1s, o2s, dvec);
    dim3 sg(64, 16, 3);
    k_sim  <<<sg, 256, 0, stream>>>(o1s, o2s, r11p, r22p, r12p, c12p);
    k_loss1<<<32, 256, 0, stream>>>(r11p, r12p, r22p, c12p, dvec, lpart);
    k_loss2<<<1, 64, 0, stream>>>(lpart, out);
}